// Round 2
// baseline (292.039 us; speedup 1.0000x reference)
//
#include <hip/hip_runtime.h>
#include <stdint.h>

#define BB 4
#define CC 256
#define HH 64
#define WWD 64
#define NN 4096
#define LOG2E 1.4426950408889634f

typedef __attribute__((ext_vector_type(8))) short short8;
typedef __attribute__((ext_vector_type(4))) float f32x4;
typedef __attribute__((ext_vector_type(16))) float f32x16;
typedef __attribute__((ext_vector_type(4))) unsigned short us4;
typedef unsigned long long ull;

__device__ __forceinline__ unsigned short f2bf(float f) {
  unsigned int u = __float_as_uint(f);
  u += 0x7fffu + ((u >> 16) & 1u);          // RNE
  return (unsigned short)(u >> 16);
}
__device__ __forceinline__ float bf2f(unsigned short h) {
  return __uint_as_float(((unsigned int)h) << 16);
}
__device__ __forceinline__ short8 ld8(const unsigned short* p) {
  return *reinterpret_cast<const short8*>(p);
}
__device__ __forceinline__ unsigned char f2fp8(float v) {   // OCP e4m3 via HW cvt (RNE)
  return (unsigned char)__builtin_amdgcn_cvt_pk_fp8_f32(v, v, 0, false);
}
__device__ __forceinline__ int rowmap(int reg, int h) {     // 32x32 C/D row map
  return (reg & 3) + 8 * (reg >> 2) + 4 * h;
}
// async global->LDS, 16B per lane; lds ptr must be wave-uniform base (HW adds lane*16)
__device__ __forceinline__ void gll16(const void* g, void* l) {
  __builtin_amdgcn_global_load_lds(
      (const __attribute__((address_space(1))) unsigned int*)g,
      (__attribute__((address_space(3))) unsigned int*)l, 16, 0, 0);
}

// ---------------- k_pre: z<8 -> transpose (+psum partials, +dwconv for x_self);
//                  z==8 -> weight fp32->bf16 cast slice
__global__ __launch_bounds__(256, 2) void k_pre(
    const float* __restrict__ xs, const float* __restrict__ xo,
    const float* __restrict__ dww, const float* __restrict__ dwb,
    const float* __restrict__ bng, const float* __restrict__ bnb,
    const float* __restrict__ bnm, const float* __restrict__ bnv,
    const float* __restrict__ qw, const float* __restrict__ kvw,
    const float* __restrict__ ow, unsigned short* __restrict__ XtS,
    unsigned short* __restrict__ XtO, unsigned short* __restrict__ localT,
    float* __restrict__ psumA, unsigned short* __restrict__ Wb) {
  __shared__ float rb3[3][64][67];
  __shared__ unsigned short sb[64][67];
  int tid = threadIdx.x;
  if (blockIdx.z == 8) {                    // weight cast
    int i = (blockIdx.x * 64 + blockIdx.y) * 1024 + tid * 4;
    const float* src;
    if (i < 65536) src = qw + i;
    else if (i < 196608) src = kvw + (i - 65536);
    else src = ow + (i - 196608);
    f32x4 v = *reinterpret_cast<const f32x4*>(src);
    us4 r;
#pragma unroll
    for (int j = 0; j < 4; ++j) r[j] = f2bf(v[j]);
    *reinterpret_cast<us4*>(Wb + i) = r;
    return;
  }
  int c0 = blockIdx.x * 64, h = blockIdx.y;
  int b = blockIdx.z >> 1, which = blockIdx.z & 1;
  const float* src = which ? xo : xs;
  int wq = tid >> 6, w = tid & 63;
  int dlo = which ? 1 : 0, dhi = which ? 1 : 2;
  for (int d = dlo; d <= dhi; ++d) {
    int hh = h + d - 1;
    bool ok = (hh >= 0 && hh < HH);
#pragma unroll
    for (int p = 0; p < 4; ++p) {
      int idx = p * 256 + tid;
      int cl = idx >> 4, ws4 = (idx & 15) * 4;
      f32x4 v = {};
      if (ok)
        v = *reinterpret_cast<const f32x4*>(
            &src[(((size_t)(b * CC + c0 + cl)) * HH + hh) * WWD + ws4]);
#pragma unroll
      for (int j = 0; j < 4; ++j) rb3[d][cl][ws4 + 1 + j] = v[j];
    }
    if (tid < 64) { rb3[d][tid][0] = 0.f; rb3[d][tid][65] = 0.f; }
  }
  __syncthreads();
  // transpose-store middle row -> Xt
  unsigned short* dst = which ? XtO : XtS;
  int n0 = h * 64, cb = (tid & 15) * 4;
#pragma unroll
  for (int i = 0; i < 4; ++i) {
    int wl = i * 16 + (tid >> 4);
    us4 r;
#pragma unroll
    for (int j = 0; j < 4; ++j) r[j] = f2bf(rb3[1][cb + j][wl + 1]);
    *reinterpret_cast<us4*>(&dst[((size_t)b * NN + n0 + wl) * CC + c0 + cb]) = r;
  }
  if (which) return;
  if (tid < 64) {                           // channel-sum partial
    float s = 0.f;
    for (int ww = 0; ww < 64; ++ww) s += rb3[1][tid][ww + 1];
    psumA[((size_t)(b * 64 + h)) * CC + c0 + tid] = s;
  }
  // depthwise 3x3 + BN + SiLU
  for (int p = 0; p < 16; ++p) {
    int cl = p * 4 + wq, c = c0 + cl;
    float acc = 0.f;
#pragma unroll
    for (int di = 0; di < 3; ++di)
#pragma unroll
      for (int dj = 0; dj < 3; ++dj)
        acc = fmaf(rb3[di][cl][w + dj], dww[c * 9 + di * 3 + dj], acc);
    float y = acc + dwb[c];
    float sc = bng[c] * rsqrtf(bnv[c] + 1e-5f);
    float v = (y - bnm[c]) * sc + bnb[c];
    sb[cl][w] = f2bf(v / (1.f + __expf(-v)));
  }
  __syncthreads();
#pragma unroll
  for (int i = 0; i < 4; ++i) {
    int wl = i * 16 + (tid >> 4);
    us4 r;
#pragma unroll
    for (int j = 0; j < 4; ++j) r[j] = sb[cb + j][wl];
    *reinterpret_cast<us4*>(&localT[((size_t)b * NN + h * WWD + wl) * CC + c0 + cb]) = r;
  }
}

// --------- fused Q,K,V projections -> fp8 outputs (LDS-transposed, coalesced);
//           + gate block (y==3). Q,K carry sqrt-split softmax scale (0.25 each).
//           K and V global layouts are XOR-pre-swizzled for k_flash8's linear
//           global_load_lds staging + conflict-free LDS reads (T2/m173 pattern):
//           Kt8[n][c'] = K[n][c' ^ ((n&31)<<3)];  Vv8[c][m'] = V[c][m' ^ (((c>>1)&7)<<3)]
//           (swizzle applied within each 64-aligned n/m tile).
__global__ __launch_bounds__(256, 4) void k_qkv(
    const unsigned short* __restrict__ XtS, const unsigned short* __restrict__ XtO,
    const unsigned short* __restrict__ Wb, const float* __restrict__ qb,
    const float* __restrict__ kvb, const float* __restrict__ psumA,
    const float* __restrict__ g1w, const float* __restrict__ g1b,
    const float* __restrict__ g2w, const float* __restrict__ g2b,
    unsigned char* __restrict__ Qt8, unsigned char* __restrict__ Kt8,
    unsigned char* __restrict__ Vv8, float* __restrict__ gate) {
  __shared__ unsigned short Xs[64][264];   // 33.8 KB; reused as fp8 transpose buffer
  int tid = threadIdx.x;
  int id = blockIdx.y;
  if (id == 3) {                            // gate (SE path), one working block
    if (blockIdx.x != 0 || blockIdx.z != 0) return;
    float* mf = (float*)&Xs[0][0];
    float* hpf = mf + 1024;
    int c = tid;
    for (int b4 = 0; b4 < 4; ++b4) {
      float s = 0.f;
      for (int hh = 0; hh < 64; ++hh) s += psumA[((size_t)(b4 * 64 + hh)) * CC + c];
      mf[b4 * 256 + c] = s * (1.f / 4096.f);
    }
    __syncthreads();
    for (int b4 = 0; b4 < 4; ++b4) {
      int j = tid >> 2, cq = tid & 3;
      float s = 0.f;
      for (int cc = cq * 64; cc < cq * 64 + 64; ++cc)
        s = fmaf(mf[b4 * 256 + cc], g1w[j * CC + cc], s);
      hpf[j * 5 + cq] = s;
      __syncthreads();
      if (tid < 64) {
        float hh = fmaxf(hpf[tid * 5] + hpf[tid * 5 + 1] + hpf[tid * 5 + 2] +
                             hpf[tid * 5 + 3] + g1b[tid], 0.f);
        float t = hh * g2w[tid];
        for (int off = 32; off; off >>= 1) t += __shfl_down(t, off, 64);
        if (tid == 0) gate[b4] = 1.f / (1.f + expf(-(t + g2b[0])));
      }
      __syncthreads();
    }
    return;
  }
  int n0 = blockIdx.x * 64, b = blockIdx.z;
  const unsigned short* Xt = (id == 0) ? XtS : XtO;
  const unsigned short* W = Wb + id * 65536;
  int wave = tid >> 6, lane = tid & 63, l31 = lane & 31, h = lane >> 5;
#pragma unroll
  for (int p = 0; p < 8; ++p) {
    int r = p * 8 + (tid >> 5), c = (tid & 31) * 8;
    *reinterpret_cast<uint4*>(&Xs[r][c]) =
        *reinterpret_cast<const uint4*>(Xt + ((size_t)b * NN + n0 + r) * CC + c);
  }
  __syncthreads();
  int o0 = wave * 64;
  f32x16 acc[4] = {};
  if (id < 2) {
#pragma unroll
    for (int t = 0; t < 16; ++t) {
      short8 a0 = ld8(&Xs[l31][t * 16 + h * 8]);
      short8 a1 = ld8(&Xs[32 + l31][t * 16 + h * 8]);
      short8 b0 = ld8(W + (size_t)(o0 + l31) * CC + t * 16 + h * 8);
      short8 b1 = ld8(W + (size_t)(o0 + 32 + l31) * CC + t * 16 + h * 8);
      acc[0] = __builtin_amdgcn_mfma_f32_32x32x16_bf16(a0, b0, acc[0], 0, 0, 0);
      acc[1] = __builtin_amdgcn_mfma_f32_32x32x16_bf16(a0, b1, acc[1], 0, 0, 0);
      acc[2] = __builtin_amdgcn_mfma_f32_32x32x16_bf16(a1, b0, acc[2], 0, 0, 0);
      acc[3] = __builtin_amdgcn_mfma_f32_32x32x16_bf16(a1, b1, acc[3], 0, 0, 0);
    }
    const float* bias = id ? kvb : qb;
    unsigned char* Out8 = id ? Kt8 : Qt8;
    __syncthreads();                        // Xs MFMA reads done
    unsigned char (*T8)[264] = reinterpret_cast<unsigned char(*)[264]>(&Xs[0][0]);
#pragma unroll
    for (int nt = 0; nt < 2; ++nt)
#pragma unroll
      for (int ot = 0; ot < 2; ++ot) {
        int o = o0 + ot * 32 + l31;
        float bv = bias[o];
#pragma unroll
        for (int reg = 0; reg < 16; ++reg) {
          int nl = nt * 32 + rowmap(reg, h);
          T8[nl][o] = f2fp8((acc[nt * 2 + ot][reg] + bv) * 0.25f);
        }
      }
    __syncthreads();
#pragma unroll
    for (int p = 0; p < 4; ++p) {
      int idx = p * 256 + tid, row = idx >> 4, cc = (idx & 15) * 16;
      int s = (id == 1) ? ((row & 31) << 3) : 0;   // K: pre-swizzle columns
      ull a0 = *reinterpret_cast<const ull*>(&T8[row][cc ^ s]);
      ull a1 = *reinterpret_cast<const ull*>(&T8[row][(cc + 8) ^ s]);
      uint4 u;
      u.x = (unsigned)a0; u.y = (unsigned)(a0 >> 32);
      u.z = (unsigned)a1; u.w = (unsigned)(a1 >> 32);
      *reinterpret_cast<uint4*>(Out8 + ((size_t)b * NN + n0 + row) * CC + cc) = u;
    }
  } else {
    // V[o][n]
#pragma unroll
    for (int t = 0; t < 16; ++t) {
      short8 a0 = ld8(W + (size_t)(o0 + l31) * CC + t * 16 + h * 8);
      short8 a1 = ld8(W + (size_t)(o0 + 32 + l31) * CC + t * 16 + h * 8);
      short8 b0 = ld8(&Xs[l31][t * 16 + h * 8]);
      short8 b1 = ld8(&Xs[32 + l31][t * 16 + h * 8]);
      acc[0] = __builtin_amdgcn_mfma_f32_32x32x16_bf16(a0, b0, acc[0], 0, 0, 0);
      acc[1] = __builtin_amdgcn_mfma_f32_32x32x16_bf16(a0, b1, acc[1], 0, 0, 0);
      acc[2] = __builtin_amdgcn_mfma_f32_32x32x16_bf16(a1, b0, acc[2], 0, 0, 0);
      acc[3] = __builtin_amdgcn_mfma_f32_32x32x16_bf16(a1, b1, acc[3], 0, 0, 0);
    }
    __syncthreads();
    unsigned char (*V8)[72] = reinterpret_cast<unsigned char(*)[72]>(&Xs[0][0]);
#pragma unroll
    for (int ot = 0; ot < 2; ++ot)
#pragma unroll
      for (int nt = 0; nt < 2; ++nt)
#pragma unroll
        for (int reg = 0; reg < 16; ++reg) {
          int o = o0 + ot * 32 + rowmap(reg, h);
          int nl = nt * 32 + l31;
          V8[o][nl] = f2fp8(acc[ot * 2 + nt][reg] + kvb[CC + o]);
        }
    __syncthreads();
#pragma unroll
    for (int p = 0; p < 4; ++p) {
      int idx = p * 256 + tid, o = idx >> 2, mm = (idx & 3) * 16;
      int s = ((o >> 1) & 7) << 3;                // V: pre-swizzle m within 64-tile
      ull a0 = *reinterpret_cast<const ull*>(&V8[o][mm ^ s]);
      ull a1 = *reinterpret_cast<const ull*>(&V8[o][(mm + 8) ^ s]);
      uint4 u;
      u.x = (unsigned)a0; u.y = (unsigned)(a0 >> 32);
      u.z = (unsigned)a1; u.w = (unsigned)(a1 >> 32);
      *reinterpret_cast<uint4*>(Vv8 + ((size_t)b * CC + o) * NN + n0 + mm) = u;
    }
  }
}

// ------------- flash attention, fp8 e4m3 everywhere (Q,K,V,P).
// Async pipeline: K/V staged via global_load_lds into LINEAR LDS (swizzle baked
// into global layout by k_qkv). V double-buffered, issued one tile ahead right
// after the stage barrier; K single-buffered, issued after the P barrier so the
// DMA flies under PV. Raw s_barrier + explicit waitcnt (no vmcnt(0) drain at
// barriers). QK operand-swapped (S^T) with TWO independent accumulators
// (k=0..127 / 128..255) to halve the dependent-MFMA chain; P stored as packed
// dwords (conflict-free). setprio(1) around MFMA clusters. LDS 53 KB -> 3 blk/CU.
__global__ __launch_bounds__(256, 3) void k_flash8(
    const unsigned char* __restrict__ Qt8, const unsigned char* __restrict__ Kt8,
    const unsigned char* __restrict__ Vv8, const unsigned short* __restrict__ localT,
    const float* __restrict__ gate, unsigned short* __restrict__ OpartA,
    unsigned short* __restrict__ OpartB,
    float* __restrict__ Lpart, unsigned short* __restrict__ fusedT) {
  __shared__ unsigned char Ks8[64][256];     // 16 KB linear; content col-swizzled
  __shared__ unsigned char Vs8[2][256][64];  // 32 KB dbuf linear; content m-swizzled
  __shared__ unsigned char Ps8[64][72];      // 4.6 KB (72: 2-way free on b64 reads)
  __shared__ float lred[2][64];
  // XCD swizzle: b = x&3 -> each XCD pinned to one b; K+V fp8 = 2 MB, L2-resident
  int b = blockIdx.x & 3, n0 = (blockIdx.x >> 2) * 64;
  int sp = blockIdx.y, nsp = gridDim.y;
  int tid = threadIdx.x, wave = tid >> 6, lane = tid & 63, l31 = lane & 31, h = lane >> 5;
  int rw = wave & 1, cw = wave >> 1;
  int wbase = tid & ~63;                     // wave-uniform lane-0 tid
  const unsigned char* qp = Qt8 + ((size_t)b * NN + n0 + rw * 32 + l31) * CC + h * 8;
  long qf[16];
#pragma unroll
  for (int t = 0; t < 16; ++t) qf[t] = *reinterpret_cast<const long*>(qp + t * 16);
  f32x16 O[4] = {};
  float lsumA = 0.f, lsumB = 0.f;
  int m_lo = (64 * sp) / nsp, m_hi = (64 * (sp + 1)) / nsp;
  const unsigned char* Kbase = Kt8 + (size_t)b * NN * CC;
  const unsigned char* Vbase = Vv8 + (size_t)b * CC * NN;
  // prologue: stage tile m_lo (V -> buf[m_lo&1], K -> Ks8)
  {
    const unsigned char* Kg = Kbase + (size_t)(m_lo * 64) * CC;
    const unsigned char* Vg = Vbase + m_lo * 64;
    unsigned char* vdst = &Vs8[m_lo & 1][0][0];
#pragma unroll
    for (int p = 0; p < 4; ++p) {
      int idx = p * 256 + tid;
      int c = idx >> 2, mm = (idx & 3) * 16;
      gll16(Vg + (size_t)c * NN + mm, vdst + (p * 256 + wbase) * 16);
      gll16(Kg + (size_t)idx * 16, &Ks8[0][0] + (p * 256 + wbase) * 16);
    }
  }
  const unsigned char* Krow = &Ks8[cw * 32 + l31][0];
  int ksw = l31 << 3;
  int vsw = ((l31 >> 1) & 7) << 3;
  for (int mt = m_lo; mt < m_hi; ++mt) {
    // ---- B: current tile staged; all prior-iter LDS reads retired (data-dep waits)
    asm volatile("s_waitcnt vmcnt(0)" ::: "memory");
    __builtin_amdgcn_s_barrier();
    __builtin_amdgcn_sched_barrier(0);
    // issue V(mt+1) -> other buffer (flies under QK+PV, waited at next B)
    {
      int mn = (mt + 1 < m_hi) ? mt + 1 : mt;
      const unsigned char* Vg = Vbase + mn * 64;
      unsigned char* vdst = &Vs8[(mt + 1) & 1][0][0];
#pragma unroll
      for (int p = 0; p < 4; ++p) {
        int idx = p * 256 + tid;
        int c = idx >> 2, mm = (idx & 3) * 16;
        gll16(Vg + (size_t)c * NN + mm, vdst + (p * 256 + wbase) * 16);
      }
    }
    __builtin_amdgcn_sched_barrier(0);
    // S^T = K Q^T (rows=m, cols=n); two independent accumulator chains
    f32x16 Sa = {}, Sb = {};
    __builtin_amdgcn_s_setprio(1);
#pragma unroll
    for (int t = 0; t < 8; ++t) {
      long kfa = *reinterpret_cast<const long*>(Krow + ((t * 16 + h * 8) ^ ksw));
      long kfb = *reinterpret_cast<const long*>(Krow + (((t + 8) * 16 + h * 8) ^ ksw));
      Sa = __builtin_amdgcn_mfma_f32_32x32x16_fp8_fp8(kfa, qf[t], Sa, 0, 0, 0);
      Sb = __builtin_amdgcn_mfma_f32_32x32x16_fp8_fp8(kfb, qf[t + 8], Sb, 0, 0, 0);
    }
    __builtin_amdgcn_s_setprio(0);
    // P = exp(S) -> packed fp8 dword stores; row-sum (row n = rw*32+l31)
#pragma unroll
    for (int r = 0; r < 4; ++r) {
      float p0 = __builtin_exp2f((Sa[4 * r + 0] + Sb[4 * r + 0]) * LOG2E);
      float p1 = __builtin_exp2f((Sa[4 * r + 1] + Sb[4 * r + 1]) * LOG2E);
      float p2 = __builtin_exp2f((Sa[4 * r + 2] + Sb[4 * r + 2]) * LOG2E);
      float p3 = __builtin_exp2f((Sa[4 * r + 3] + Sb[4 * r + 3]) * LOG2E);
      lsumA += p0 + p1;
      lsumB += p2 + p3;
      unsigned u = __builtin_amdgcn_cvt_pk_fp8_f32(p0, p1, 0, false);
      u = __builtin_amdgcn_cvt_pk_fp8_f32(p2, p3, u, true);
      *reinterpret_cast<unsigned*>(&Ps8[rw * 32 + l31][cw * 32 + 8 * r + 4 * h]) = u;
    }
    // ---- C: P visible to partner wave; Ks8 QK reads retired in all waves
    asm volatile("s_waitcnt lgkmcnt(0)" ::: "memory");
    __builtin_amdgcn_s_barrier();
    __builtin_amdgcn_sched_barrier(0);
    // issue K(mt+1) -> Ks8 (flies under PV, waited at next B)
    {
      int mn = (mt + 1 < m_hi) ? mt + 1 : mt;
      const unsigned char* Kg = Kbase + (size_t)(mn * 64) * CC;
#pragma unroll
      for (int p = 0; p < 4; ++p)
        gll16(Kg + (size_t)(p * 256 + tid) * 16, &Ks8[0][0] + (p * 256 + wbase) * 16);
    }
    __builtin_amdgcn_sched_barrier(0);
    // O += P V^T : rows rw*32, cols cw*128, k=64; 4 independent chains
    const unsigned char (*Vc)[64] = Vs8[mt & 1];
    __builtin_amdgcn_s_setprio(1);
#pragma unroll
    for (int t = 0; t < 4; ++t) {
      long pf = *reinterpret_cast<const long*>(&Ps8[rw * 32 + l31][t * 16 + h * 8]);
#pragma unroll
      for (int ct = 0; ct < 4; ++ct) {
        long vf = *reinterpret_cast<const long*>(
            &Vc[cw * 128 + ct * 32 + l31][(t * 16 + h * 8) ^ vsw]);
        O[ct] = __builtin_amdgcn_mfma_f32_32x32x16_fp8_fp8(pf, vf, O[ct], 0, 0, 0);
      }
    }
    __builtin_amdgcn_s_setprio(0);
  }
  asm volatile("s_waitcnt vmcnt(0)" ::: "memory");   // drain tail prefetches
  float lsum = lsumA + lsumB;
  // combine the two m-halves (h) then the two m-tiles (cw)
  lsum += __shfl_xor(lsum, 32, 64);
  __syncthreads();
  if (h == 0) lred[cw][rw * 32 + l31] = lsum;
  __syncthreads();
  if (nsp == 1) {
    float* ltot = reinterpret_cast<float*>(&Ps8[0][0]);   // Ps8 dead here
    if (tid < 64) ltot[tid] = lred[0][tid] + lred[1][tid];
    __syncthreads();
    float gv = gate[b];
    float inv[16];
#pragma unroll
    for (int reg = 0; reg < 16; ++reg)
      inv[reg] = gv / ltot[rw * 32 + rowmap(reg, h)];
#pragma unroll
    for (int ct = 0; ct < 4; ++ct)
#pragma unroll
      for (int reg = 0; reg < 16; ++reg) {
        int n = n0 + rw * 32 + rowmap(reg, h);
        int c = cw * 128 + ct * 32 + l31;
        size_t idx = ((size_t)b * NN + n) * CC + c;
        fusedT[idx] = f2bf(bf2f(localT[idx]) + O[ct][reg] * inv[reg]);
      }
  } else {
    if (tid < 64) Lpart[(size_t)(b * nsp + sp) * NN + n0 + tid] = lred[0][tid] + lred[1][tid];
    unsigned short* Op;
    size_t slab;
    if (sp == 0) { Op = OpartA; slab = (size_t)b * NN; }
    else { Op = OpartB; slab = (size_t)(b * (nsp - 1) + (sp - 1)) * NN; }
#pragma unroll
    for (int ct = 0; ct < 4; ++ct)
#pragma unroll
      for (int reg = 0; reg < 16; ++reg) {
        int n = n0 + rw * 32 + rowmap(reg, h);
        int c = cw * 128 + ct * 32 + l31;
        Op[(slab + n) * CC + c] = f2bf(O[ct][reg]);
      }
  }
}

// --------- out projection with fused split-combine (Opart bf16)
__global__ __launch_bounds__(256, 4) void k_out(
    const unsigned short* __restrict__ W, const float* __restrict__ ob,
    const float* __restrict__ gate, const unsigned short* __restrict__ localT,
    const unsigned short* __restrict__ OpartA, const unsigned short* __restrict__ OpartB,
    const float* __restrict__ Lpart,
    const unsigned short* __restrict__ fusedT, float* __restrict__ out, int nsp) {
  __shared__ unsigned short Xs[64][264];
  int n0 = blockIdx.x * 64, o0 = blockIdx.y * 128, b = blockIdx.z;
  int tid = threadIdx.x, wave = tid >> 6, lane = tid & 63, l31 = lane & 31, h = lane >> 5;
  if (nsp > 1) {
    float gv = gate[b];
#pragma unroll
    for (int p = 0; p < 8; ++p) {
      int r = p * 8 + (tid >> 5), cc = (tid & 31) * 8;
      int n = n0 + r;
      float lsum = 0.f;
      for (int sp = 0; sp < nsp; ++sp) lsum += Lpart[(size_t)(b * nsp + sp) * NN + n];
      float g = gv / lsum;
      float ov[8] = {};
      for (int sp = 0; sp < nsp; ++sp) {
        const unsigned short* Op;
        size_t slab;
        if (sp == 0) { Op = OpartA; slab = (size_t)b * NN; }
        else { Op = OpartB; slab = (size_t)(b * (nsp - 1) + (sp - 1)) * NN; }
        short8 x = ld8(Op + (slab + n) * CC + cc);
#pragma unroll
        for (int j = 0; j < 8; ++j) ov[j] += bf2f(((unsigned short*)&x)[j]);
      }
      const unsigned short* lp = localT + ((size_t)b * NN + n) * CC + cc;
      short8 lv = ld8(lp);
      us4 r0, r1;
#pragma unroll
      for (int j = 0; j < 4; ++j) {
        r0[j] = f2bf(bf2f(((unsigned short*)&lv)[j]) + ov[j] * g);
        r1[j] = f2bf(bf2f(((unsigned short*)&lv)[j + 4]) + ov[j + 4] * g);
      }
      *reinterpret_cast<us4*>(&Xs[r][cc]) = r0;
      *reinterpret_cast<us4*>(&Xs[r][cc + 4]) = r1;
    }
  } else {
#pragma unroll
    for (int p = 0; p < 8; ++p) {
      int r = p * 8 + (tid >> 5), c = (tid & 31) * 8;
      *reinterpret_cast<uint4*>(&Xs[r][c]) =
          *reinterpret_cast<const uint4*>(fusedT + ((size_t)b * NN + n0 + r) * CC + c);
    }
  }
  int obase = o0 + wave * 32;
  short8 af[16];
#pragma unroll
  for (int t = 0; t < 16; ++t) af[t] = ld8(W + (size_t)(obase + l31) * CC + t * 16 + h * 8);
  __syncthreads();
  f32x16 acc[2] = {};
#pragma unroll
  for (int t = 0; t < 16; ++t) {
    short8 b0 = ld8(&Xs[l31][t * 16 + h * 8]);
    short8 b1 = ld8(&Xs[32 + l31][t * 16 + h * 8]);
    acc[0] = __builtin_amdgcn_mfma_f32_32x32x16_bf16(af[t], b0, acc[0], 0, 0, 0);
    acc[1] = __builtin_amdgcn_mfma_f32_32x32x16_bf16(af[t], b1, acc[1], 0, 0, 0);
  }
#pragma unroll
  for (int nt = 0; nt < 2; ++nt)
#pragma unroll
    for (int reg = 0; reg < 16; ++reg) {
      int o = obase + rowmap(reg, h);
      int n = n0 + nt * 32 + l31;
      out[((size_t)b * CC + o) * NN + n] = acc[nt][reg] + ob[o];
    }
}

// ---------------------------------------------------------------------------- launch
extern "C" void kernel_launch(void* const* d_in, const int* in_sizes, int n_in,
                              void* d_out, int out_size, void* d_ws, size_t ws_size,
                              hipStream_t stream) {
  const float* xs  = (const float*)d_in[0];
  const float* xo  = (const float*)d_in[1];
  const float* qw  = (const float*)d_in[2];
  const float* qb  = (const float*)d_in[3];
  const float* kvw = (const float*)d_in[4];
  const float* kvb = (const float*)d_in[5];
  const float* g1w = (const float*)d_in[6];
  const float* g1b = (const float*)d_in[7];
  const float* g2w = (const float*)d_in[8];
  const float* g2b = (const float*)d_in[9];
  const float* dww = (const float*)d_in[10];
  const float* dwb = (const float*)d_in[11];
  const float* bng = (const float*)d_in[12];
  const float* bnb = (const float*)d_in[13];
  const float* bnm = (const float*)d_in[14];
  const float* bnv = (const float*)d_in[15];
  const float* ow  = (const float*)d_in[16];
  const float* ob  = (const float*)d_in[17];
  float* out = (float*)d_out;
  char* ws = (char*)d_ws;

  const size_t SZ  = (size_t)BB * NN * CC * 2;            // 8 MB bf16 tensor
  const size_t SZ8 = (size_t)BB * NN * CC;                // 4 MB fp8 tensor
  unsigned short* XtS    = (unsigned short*)(ws);
  unsigned short* XtO    = (unsigned short*)(ws + SZ);
  unsigned short* localT = (unsigned short*)(ws + 2 * SZ);
  unsigned char*  Qt8    = (unsigned char*)(ws + 3 * SZ);
  unsigned char*  Kt8    = (unsigned char*)(ws + 3 * SZ + SZ8);
  unsigned char*  Vv8    = (unsigned char*)(ws + 3 * SZ + 2 * SZ8);
  unsigned short* Wb     = (unsigned short*)(ws + 3 * SZ + 3 * SZ8);   // 512 KB
  float* psumA = (float*)(ws + 3 * SZ + 3 * SZ8 + 524288);             // 256 KB
  float* gate  = (float*)(ws + 3 * SZ + 3 * SZ8 + 524288 + 262144);    // 16 B
  size_t tail  = 3 * SZ + 3 * SZ8 + 524288 + 262144 + 4096;
  float* Lpart = (float*)(ws + tail);                                  // 256 KB
  // Opart split-0 slab aliases XtO (dead after k_qkv); remaining slabs in tail.
  unsigned short* OpartA = XtO;
  unsigned short* OpartB = (unsigned short*)(ws + tail + 262144);      // (S-1)*8 MB
  unsigned short* fusedT = XtS;                                        // dead after k_qkv

  size_t base = tail + 262144;
  int S = 1;
  if (ws_size >= base + 2ull * SZ) S = 3;          // 768 blocks = 3/CU
  else if (ws_size >= base + 1ull * SZ) S = 2;

  k_pre<<<dim3(4, 64, 9), 256, 0, stream>>>(xs, xo, dww, dwb, bng, bnb, bnm, bnv,
                                            qw, kvw, ow, XtS, XtO, localT, psumA, Wb);
  k_qkv<<<dim3(64, 4, 4), 256, 0, stream>>>(XtS, XtO, Wb, qb, kvb, psumA,
                                            g1w, g1b, g2w, g2b, Qt8, Kt8, Vv8, gate);
  k_flash8<<<dim3(256, S), 256, 0, stream>>>(Qt8, Kt8, Vv8, localT, gate, OpartA,
                                             OpartB, Lpart, fusedT);
  k_out<<<dim3(64, 2, 4), 256, 0, stream>>>(Wb + 196608, ob, gate, localT,
                                            OpartA, OpartB, Lpart, fusedT, out, S);
}

// Round 3
// 246.620 us; speedup vs baseline: 1.1842x; 1.1842x over previous
//
#include <hip/hip_runtime.h>
#include <stdint.h>

#define BB 4
#define CC 256
#define HH 64
#define WWD 64
#define NN 4096
#define LOG2E 1.4426950408889634f

typedef __attribute__((ext_vector_type(8))) short short8;
typedef __attribute__((ext_vector_type(4))) float f32x4;
typedef __attribute__((ext_vector_type(16))) float f32x16;
typedef __attribute__((ext_vector_type(4))) unsigned short us4;
typedef unsigned long long ull;

__device__ __forceinline__ unsigned short f2bf(float f) {
  unsigned int u = __float_as_uint(f);
  u += 0x7fffu + ((u >> 16) & 1u);          // RNE
  return (unsigned short)(u >> 16);
}
__device__ __forceinline__ float bf2f(unsigned short h) {
  return __uint_as_float(((unsigned int)h) << 16);
}
__device__ __forceinline__ short8 ld8(const unsigned short* p) {
  return *reinterpret_cast<const short8*>(p);
}
__device__ __forceinline__ unsigned char f2fp8(float v) {   // OCP e4m3 via HW cvt (RNE)
  return (unsigned char)__builtin_amdgcn_cvt_pk_fp8_f32(v, v, 0, false);
}
__device__ __forceinline__ int rowmap(int reg, int h) {     // 32x32 C/D row map
  return (reg & 3) + 8 * (reg >> 2) + 4 * h;
}
// async global->LDS, 16B per lane; lds ptr must be wave-uniform base (HW adds lane*16)
__device__ __forceinline__ void gll16(const void* g, void* l) {
  __builtin_amdgcn_global_load_lds(
      (const __attribute__((address_space(1))) unsigned int*)g,
      (__attribute__((address_space(3))) unsigned int*)l, 16, 0, 0);
}

// ---------------- k_pre: z<8 -> transpose (+psum partials, +dwconv for x_self);
//                  z==8 -> weight fp32->bf16 cast slice
__global__ __launch_bounds__(256, 2) void k_pre(
    const float* __restrict__ xs, const float* __restrict__ xo,
    const float* __restrict__ dww, const float* __restrict__ dwb,
    const float* __restrict__ bng, const float* __restrict__ bnb,
    const float* __restrict__ bnm, const float* __restrict__ bnv,
    const float* __restrict__ qw, const float* __restrict__ kvw,
    const float* __restrict__ ow, unsigned short* __restrict__ XtS,
    unsigned short* __restrict__ XtO, unsigned short* __restrict__ localT,
    float* __restrict__ psumA, unsigned short* __restrict__ Wb) {
  __shared__ float rb3[3][64][67];
  __shared__ unsigned short sb[64][67];
  int tid = threadIdx.x;
  if (blockIdx.z == 8) {                    // weight cast
    int i = (blockIdx.x * 64 + blockIdx.y) * 1024 + tid * 4;
    const float* src;
    if (i < 65536) src = qw + i;
    else if (i < 196608) src = kvw + (i - 65536);
    else src = ow + (i - 196608);
    f32x4 v = *reinterpret_cast<const f32x4*>(src);
    us4 r;
#pragma unroll
    for (int j = 0; j < 4; ++j) r[j] = f2bf(v[j]);
    *reinterpret_cast<us4*>(Wb + i) = r;
    return;
  }
  int c0 = blockIdx.x * 64, h = blockIdx.y;
  int b = blockIdx.z >> 1, which = blockIdx.z & 1;
  const float* src = which ? xo : xs;
  int wq = tid >> 6, w = tid & 63;
  int dlo = which ? 1 : 0, dhi = which ? 1 : 2;
  for (int d = dlo; d <= dhi; ++d) {
    int hh = h + d - 1;
    bool ok = (hh >= 0 && hh < HH);
#pragma unroll
    for (int p = 0; p < 4; ++p) {
      int idx = p * 256 + tid;
      int cl = idx >> 4, ws4 = (idx & 15) * 4;
      f32x4 v = {};
      if (ok)
        v = *reinterpret_cast<const f32x4*>(
            &src[(((size_t)(b * CC + c0 + cl)) * HH + hh) * WWD + ws4]);
#pragma unroll
      for (int j = 0; j < 4; ++j) rb3[d][cl][ws4 + 1 + j] = v[j];
    }
    if (tid < 64) { rb3[d][tid][0] = 0.f; rb3[d][tid][65] = 0.f; }
  }
  __syncthreads();
  // transpose-store middle row -> Xt
  unsigned short* dst = which ? XtO : XtS;
  int n0 = h * 64, cb = (tid & 15) * 4;
#pragma unroll
  for (int i = 0; i < 4; ++i) {
    int wl = i * 16 + (tid >> 4);
    us4 r;
#pragma unroll
    for (int j = 0; j < 4; ++j) r[j] = f2bf(rb3[1][cb + j][wl + 1]);
    *reinterpret_cast<us4*>(&dst[((size_t)b * NN + n0 + wl) * CC + c0 + cb]) = r;
  }
  if (which) return;
  if (tid < 64) {                           // channel-sum partial
    float s = 0.f;
    for (int ww = 0; ww < 64; ++ww) s += rb3[1][tid][ww + 1];
    psumA[((size_t)(b * 64 + h)) * CC + c0 + tid] = s;
  }
  // depthwise 3x3 + BN + SiLU
  for (int p = 0; p < 16; ++p) {
    int cl = p * 4 + wq, c = c0 + cl;
    float acc = 0.f;
#pragma unroll
    for (int di = 0; di < 3; ++di)
#pragma unroll
      for (int dj = 0; dj < 3; ++dj)
        acc = fmaf(rb3[di][cl][w + dj], dww[c * 9 + di * 3 + dj], acc);
    float y = acc + dwb[c];
    float sc = bng[c] * rsqrtf(bnv[c] + 1e-5f);
    float v = (y - bnm[c]) * sc + bnb[c];
    sb[cl][w] = f2bf(v / (1.f + __expf(-v)));
  }
  __syncthreads();
#pragma unroll
  for (int i = 0; i < 4; ++i) {
    int wl = i * 16 + (tid >> 4);
    us4 r;
#pragma unroll
    for (int j = 0; j < 4; ++j) r[j] = sb[cb + j][wl];
    *reinterpret_cast<us4*>(&localT[((size_t)b * NN + h * WWD + wl) * CC + c0 + cb]) = r;
  }
}

// --------- fused Q,K,V projections -> fp8 outputs (LDS-transposed, coalesced);
//           + gate block (y==3). Q,K carry sqrt-split softmax scale (0.25 each).
//           K and V global layouts are XOR-pre-swizzled for k_flash8's linear
//           global_load_lds staging + conflict-free LDS reads (T2/m173 pattern):
//           Kt8[n][c'] = K[n][c' ^ ((n&31)<<3)];  Vv8[c][m'] = V[c][m' ^ (((c>>1)&7)<<3)]
//           (swizzle applied within each 64-aligned n/m tile).
__global__ __launch_bounds__(256, 4) void k_qkv(
    const unsigned short* __restrict__ XtS, const unsigned short* __restrict__ XtO,
    const unsigned short* __restrict__ Wb, const float* __restrict__ qb,
    const float* __restrict__ kvb, const float* __restrict__ psumA,
    const float* __restrict__ g1w, const float* __restrict__ g1b,
    const float* __restrict__ g2w, const float* __restrict__ g2b,
    unsigned char* __restrict__ Qt8, unsigned char* __restrict__ Kt8,
    unsigned char* __restrict__ Vv8, float* __restrict__ gate) {
  __shared__ unsigned short Xs[64][264];   // 33.8 KB; reused as fp8 transpose buffer
  int tid = threadIdx.x;
  int id = blockIdx.y;
  if (id == 3) {                            // gate (SE path), one working block
    if (blockIdx.x != 0 || blockIdx.z != 0) return;
    float* mf = (float*)&Xs[0][0];
    float* hpf = mf + 1024;
    int c = tid;
    for (int b4 = 0; b4 < 4; ++b4) {
      float s = 0.f;
      for (int hh = 0; hh < 64; ++hh) s += psumA[((size_t)(b4 * 64 + hh)) * CC + c];
      mf[b4 * 256 + c] = s * (1.f / 4096.f);
    }
    __syncthreads();
    for (int b4 = 0; b4 < 4; ++b4) {
      int j = tid >> 2, cq = tid & 3;
      float s = 0.f;
      for (int cc = cq * 64; cc < cq * 64 + 64; ++cc)
        s = fmaf(mf[b4 * 256 + cc], g1w[j * CC + cc], s);
      hpf[j * 5 + cq] = s;
      __syncthreads();
      if (tid < 64) {
        float hh = fmaxf(hpf[tid * 5] + hpf[tid * 5 + 1] + hpf[tid * 5 + 2] +
                             hpf[tid * 5 + 3] + g1b[tid], 0.f);
        float t = hh * g2w[tid];
        for (int off = 32; off; off >>= 1) t += __shfl_down(t, off, 64);
        if (tid == 0) gate[b4] = 1.f / (1.f + expf(-(t + g2b[0])));
      }
      __syncthreads();
    }
    return;
  }
  int n0 = blockIdx.x * 64, b = blockIdx.z;
  const unsigned short* Xt = (id == 0) ? XtS : XtO;
  const unsigned short* W = Wb + id * 65536;
  int wave = tid >> 6, lane = tid & 63, l31 = lane & 31, h = lane >> 5;
#pragma unroll
  for (int p = 0; p < 8; ++p) {
    int r = p * 8 + (tid >> 5), c = (tid & 31) * 8;
    *reinterpret_cast<uint4*>(&Xs[r][c]) =
        *reinterpret_cast<const uint4*>(Xt + ((size_t)b * NN + n0 + r) * CC + c);
  }
  __syncthreads();
  int o0 = wave * 64;
  f32x16 acc[4] = {};
  if (id < 2) {
#pragma unroll
    for (int t = 0; t < 16; ++t) {
      short8 a0 = ld8(&Xs[l31][t * 16 + h * 8]);
      short8 a1 = ld8(&Xs[32 + l31][t * 16 + h * 8]);
      short8 b0 = ld8(W + (size_t)(o0 + l31) * CC + t * 16 + h * 8);
      short8 b1 = ld8(W + (size_t)(o0 + 32 + l31) * CC + t * 16 + h * 8);
      acc[0] = __builtin_amdgcn_mfma_f32_32x32x16_bf16(a0, b0, acc[0], 0, 0, 0);
      acc[1] = __builtin_amdgcn_mfma_f32_32x32x16_bf16(a0, b1, acc[1], 0, 0, 0);
      acc[2] = __builtin_amdgcn_mfma_f32_32x32x16_bf16(a1, b0, acc[2], 0, 0, 0);
      acc[3] = __builtin_amdgcn_mfma_f32_32x32x16_bf16(a1, b1, acc[3], 0, 0, 0);
    }
    const float* bias = id ? kvb : qb;
    unsigned char* Out8 = id ? Kt8 : Qt8;
    __syncthreads();                        // Xs MFMA reads done
    unsigned char (*T8)[264] = reinterpret_cast<unsigned char(*)[264]>(&Xs[0][0]);
#pragma unroll
    for (int nt = 0; nt < 2; ++nt)
#pragma unroll
      for (int ot = 0; ot < 2; ++ot) {
        int o = o0 + ot * 32 + l31;
        float bv = bias[o];
#pragma unroll
        for (int reg = 0; reg < 16; ++reg) {
          int nl = nt * 32 + rowmap(reg, h);
          T8[nl][o] = f2fp8((acc[nt * 2 + ot][reg] + bv) * 0.25f);
        }
      }
    __syncthreads();
#pragma unroll
    for (int p = 0; p < 4; ++p) {
      int idx = p * 256 + tid, row = idx >> 4, cc = (idx & 15) * 16;
      int s = (id == 1) ? ((row & 31) << 3) : 0;   // K: pre-swizzle columns
      ull a0 = *reinterpret_cast<const ull*>(&T8[row][cc ^ s]);
      ull a1 = *reinterpret_cast<const ull*>(&T8[row][(cc + 8) ^ s]);
      uint4 u;
      u.x = (unsigned)a0; u.y = (unsigned)(a0 >> 32);
      u.z = (unsigned)a1; u.w = (unsigned)(a1 >> 32);
      *reinterpret_cast<uint4*>(Out8 + ((size_t)b * NN + n0 + row) * CC + cc) = u;
    }
  } else {
    // V[o][n]
#pragma unroll
    for (int t = 0; t < 16; ++t) {
      short8 a0 = ld8(W + (size_t)(o0 + l31) * CC + t * 16 + h * 8);
      short8 a1 = ld8(W + (size_t)(o0 + 32 + l31) * CC + t * 16 + h * 8);
      short8 b0 = ld8(&Xs[l31][t * 16 + h * 8]);
      short8 b1 = ld8(&Xs[32 + l31][t * 16 + h * 8]);
      acc[0] = __builtin_amdgcn_mfma_f32_32x32x16_bf16(a0, b0, acc[0], 0, 0, 0);
      acc[1] = __builtin_amdgcn_mfma_f32_32x32x16_bf16(a0, b1, acc[1], 0, 0, 0);
      acc[2] = __builtin_amdgcn_mfma_f32_32x32x16_bf16(a1, b0, acc[2], 0, 0, 0);
      acc[3] = __builtin_amdgcn_mfma_f32_32x32x16_bf16(a1, b1, acc[3], 0, 0, 0);
    }
    __syncthreads();
    unsigned char (*V8)[72] = reinterpret_cast<unsigned char(*)[72]>(&Xs[0][0]);
#pragma unroll
    for (int ot = 0; ot < 2; ++ot)
#pragma unroll
      for (int nt = 0; nt < 2; ++nt)
#pragma unroll
        for (int reg = 0; reg < 16; ++reg) {
          int o = o0 + ot * 32 + rowmap(reg, h);
          int nl = nt * 32 + l31;
          V8[o][nl] = f2fp8(acc[ot * 2 + nt][reg] + kvb[CC + o]);
        }
    __syncthreads();
#pragma unroll
    for (int p = 0; p < 4; ++p) {
      int idx = p * 256 + tid, o = idx >> 2, mm = (idx & 3) * 16;
      int s = ((o >> 1) & 7) << 3;                // V: pre-swizzle m within 64-tile
      ull a0 = *reinterpret_cast<const ull*>(&V8[o][mm ^ s]);
      ull a1 = *reinterpret_cast<const ull*>(&V8[o][(mm + 8) ^ s]);
      uint4 u;
      u.x = (unsigned)a0; u.y = (unsigned)(a0 >> 32);
      u.z = (unsigned)a1; u.w = (unsigned)(a1 >> 32);
      *reinterpret_cast<uint4*>(Vv8 + ((size_t)b * CC + o) * NN + n0 + mm) = u;
    }
  }
}

// ------------- flash attention, fp8 e4m3 everywhere (Q,K,V,P).
// LDS kept at 37.9 KB (<= 5 x 8KB alloc units) so 3 blocks/CU stay resident
// (54 KB rounded to 7 units -> only 2/CU resident; that was round-2's 1.5-pass
// serialization). Single K buf + single V buf; pipeline keeps both DMAs covered:
//   [A: vmcnt(0)+barrier] -> issue V(mt) -> QK (covers V flight) -> exp/pack-P
//   -> [P: lgkm(0)+barrier] -> issue K(mt+1) -> vmcnt(4) (V in, K flying) -> PV.
// Swizzles baked into global K/V layouts by k_qkv; P stored as packed dwords.
__global__ __launch_bounds__(256, 3) void k_flash8(
    const unsigned char* __restrict__ Qt8, const unsigned char* __restrict__ Kt8,
    const unsigned char* __restrict__ Vv8, const unsigned short* __restrict__ localT,
    const float* __restrict__ gate, unsigned short* __restrict__ OpartA,
    unsigned short* __restrict__ OpartB,
    float* __restrict__ Lpart, unsigned short* __restrict__ fusedT) {
  __shared__ unsigned char Ks8[64][256];     // 16 KB linear; content col-swizzled
  __shared__ unsigned char Vs8[256][64];     // 16 KB linear; content m-swizzled
  __shared__ unsigned char Ps8[64][72];      // 4.6 KB (72: 2-way (free) b64 reads)
  __shared__ float lred[2][64];
  // XCD swizzle: b = x&3 -> each XCD pinned to one b; K+V fp8 = 2 MB, L2-resident
  int b = blockIdx.x & 3, n0 = (blockIdx.x >> 2) * 64;
  int sp = blockIdx.y, nsp = gridDim.y;
  int tid = threadIdx.x, wave = tid >> 6, lane = tid & 63, l31 = lane & 31, h = lane >> 5;
  int rw = wave & 1, cw = wave >> 1;
  int wbase = tid & ~63;                     // wave-uniform lane-0 tid
  const unsigned char* qp = Qt8 + ((size_t)b * NN + n0 + rw * 32 + l31) * CC + h * 8;
  long qf[16];
#pragma unroll
  for (int t = 0; t < 16; ++t) qf[t] = *reinterpret_cast<const long*>(qp + t * 16);
  f32x16 O[4] = {};
  float lsumA = 0.f, lsumB = 0.f;
  int m_lo = (64 * sp) / nsp, m_hi = (64 * (sp + 1)) / nsp;
  const unsigned char* Kbase = Kt8 + (size_t)b * NN * CC;
  const unsigned char* Vbase = Vv8 + (size_t)b * CC * NN;
  // prologue: issue K(m_lo)
  {
    const unsigned char* Kg = Kbase + (size_t)(m_lo * 64) * CC;
#pragma unroll
    for (int p = 0; p < 4; ++p)
      gll16(Kg + (size_t)(p * 256 + tid) * 16, &Ks8[0][0] + (p * 256 + wbase) * 16);
  }
  const unsigned char* Krow = &Ks8[cw * 32 + l31][0];
  int ksw = l31 << 3;
  int vsw = ((l31 >> 1) & 7) << 3;
  for (int mt = m_lo; mt < m_hi; ++mt) {
    // ---- A: K(mt) arrived; all prior-iter Vs8/Ps8 LDS reads retired
    asm volatile("s_waitcnt vmcnt(0)" ::: "memory");
    __builtin_amdgcn_s_barrier();
    __builtin_amdgcn_sched_barrier(0);
    // issue V(mt) -> Vs8 (arrives during QK+exp; waited at vmcnt(4) below)
    {
      const unsigned char* Vg = Vbase + mt * 64;
#pragma unroll
      for (int p = 0; p < 4; ++p) {
        int idx = p * 256 + tid;
        int c = idx >> 2, mm = (idx & 3) * 16;
        gll16(Vg + (size_t)c * NN + mm, &Vs8[0][0] + (p * 256 + wbase) * 16);
      }
    }
    __builtin_amdgcn_sched_barrier(0);
    // S^T = K Q^T (rows=m, cols=n); two independent accumulator chains
    f32x16 Sa = {}, Sb = {};
    __builtin_amdgcn_s_setprio(1);
#pragma unroll
    for (int t = 0; t < 8; ++t) {
      long kfa = *reinterpret_cast<const long*>(Krow + ((t * 16 + h * 8) ^ ksw));
      long kfb = *reinterpret_cast<const long*>(Krow + (((t + 8) * 16 + h * 8) ^ ksw));
      Sa = __builtin_amdgcn_mfma_f32_32x32x16_fp8_fp8(kfa, qf[t], Sa, 0, 0, 0);
      Sb = __builtin_amdgcn_mfma_f32_32x32x16_fp8_fp8(kfb, qf[t + 8], Sb, 0, 0, 0);
    }
    __builtin_amdgcn_s_setprio(0);
    // P = exp(S) -> packed fp8 dword stores; row-sum (row n = rw*32+l31)
#pragma unroll
    for (int r = 0; r < 4; ++r) {
      float p0 = __builtin_exp2f((Sa[4 * r + 0] + Sb[4 * r + 0]) * LOG2E);
      float p1 = __builtin_exp2f((Sa[4 * r + 1] + Sb[4 * r + 1]) * LOG2E);
      float p2 = __builtin_exp2f((Sa[4 * r + 2] + Sb[4 * r + 2]) * LOG2E);
      float p3 = __builtin_exp2f((Sa[4 * r + 3] + Sb[4 * r + 3]) * LOG2E);
      lsumA += p0 + p1;
      lsumB += p2 + p3;
      unsigned u = __builtin_amdgcn_cvt_pk_fp8_f32(p0, p1, 0, false);
      u = __builtin_amdgcn_cvt_pk_fp8_f32(p2, p3, u, true);
      *reinterpret_cast<unsigned*>(&Ps8[rw * 32 + l31][cw * 32 + 8 * r + 4 * h]) = u;
    }
    // ---- P: P visible to partner wave; Ks8 QK reads retired in all waves
    asm volatile("s_waitcnt lgkmcnt(0)" ::: "memory");
    __builtin_amdgcn_s_barrier();
    __builtin_amdgcn_sched_barrier(0);
    // issue K(mt+1) -> Ks8 (flies under PV, waited at next A)
    {
      int mn = (mt + 1 < m_hi) ? mt + 1 : mt;
      const unsigned char* Kg = Kbase + (size_t)(mn * 64) * CC;
#pragma unroll
      for (int p = 0; p < 4; ++p)
        gll16(Kg + (size_t)(p * 256 + tid) * 16, &Ks8[0][0] + (p * 256 + wbase) * 16);
    }
    __builtin_amdgcn_sched_barrier(0);
    // wait V(mt) landed (its 4 DMAs are the oldest; K's 4 may stay in flight)
    asm volatile("s_waitcnt vmcnt(4)" ::: "memory");
    __builtin_amdgcn_sched_barrier(0);
    // O += P V^T : rows rw*32, cols cw*128, k=64; 4 independent chains
    __builtin_amdgcn_s_setprio(1);
#pragma unroll
    for (int t = 0; t < 4; ++t) {
      long pf = *reinterpret_cast<const long*>(&Ps8[rw * 32 + l31][t * 16 + h * 8]);
#pragma unroll
      for (int ct = 0; ct < 4; ++ct) {
        long vf = *reinterpret_cast<const long*>(
            &Vs8[cw * 128 + ct * 32 + l31][(t * 16 + h * 8) ^ vsw]);
        O[ct] = __builtin_amdgcn_mfma_f32_32x32x16_fp8_fp8(pf, vf, O[ct], 0, 0, 0);
      }
    }
    __builtin_amdgcn_s_setprio(0);
  }
  asm volatile("s_waitcnt vmcnt(0)" ::: "memory");   // drain tail K prefetch
  float lsum = lsumA + lsumB;
  // combine the two m-halves (h) then the two m-tiles (cw)
  lsum += __shfl_xor(lsum, 32, 64);
  __syncthreads();
  if (h == 0) lred[cw][rw * 32 + l31] = lsum;
  __syncthreads();
  if (nsp == 1) {
    float* ltot = reinterpret_cast<float*>(&Ps8[0][0]);   // Ps8 dead here
    if (tid < 64) ltot[tid] = lred[0][tid] + lred[1][tid];
    __syncthreads();
    float gv = gate[b];
    float inv[16];
#pragma unroll
    for (int reg = 0; reg < 16; ++reg)
      inv[reg] = gv / ltot[rw * 32 + rowmap(reg, h)];
#pragma unroll
    for (int ct = 0; ct < 4; ++ct)
#pragma unroll
      for (int reg = 0; reg < 16; ++reg) {
        int n = n0 + rw * 32 + rowmap(reg, h);
        int c = cw * 128 + ct * 32 + l31;
        size_t idx = ((size_t)b * NN + n) * CC + c;
        fusedT[idx] = f2bf(bf2f(localT[idx]) + O[ct][reg] * inv[reg]);
      }
  } else {
    if (tid < 64) Lpart[(size_t)(b * nsp + sp) * NN + n0 + tid] = lred[0][tid] + lred[1][tid];
    unsigned short* Op;
    size_t slab;
    if (sp == 0) { Op = OpartA; slab = (size_t)b * NN; }
    else { Op = OpartB; slab = (size_t)(b * (nsp - 1) + (sp - 1)) * NN; }
#pragma unroll
    for (int ct = 0; ct < 4; ++ct)
#pragma unroll
      for (int reg = 0; reg < 16; ++reg) {
        int n = n0 + rw * 32 + rowmap(reg, h);
        int c = cw * 128 + ct * 32 + l31;
        Op[(slab + n) * CC + c] = f2bf(O[ct][reg]);
      }
  }
}

// --------- out projection with fused split-combine (Opart bf16)
__global__ __launch_bounds__(256, 4) void k_out(
    const unsigned short* __restrict__ W, const float* __restrict__ ob,
    const float* __restrict__ gate, const unsigned short* __restrict__ localT,
    const unsigned short* __restrict__ OpartA, const unsigned short* __restrict__ OpartB,
    const float* __restrict__ Lpart,
    const unsigned short* __restrict__ fusedT, float* __restrict__ out, int nsp) {
  __shared__ unsigned short Xs[64][264];
  int n0 = blockIdx.x * 64, o0 = blockIdx.y * 128, b = blockIdx.z;
  int tid = threadIdx.x, wave = tid >> 6, lane = tid & 63, l31 = lane & 31, h = lane >> 5;
  if (nsp > 1) {
    float gv = gate[b];
#pragma unroll
    for (int p = 0; p < 8; ++p) {
      int r = p * 8 + (tid >> 5), cc = (tid & 31) * 8;
      int n = n0 + r;
      float lsum = 0.f;
      for (int sp = 0; sp < nsp; ++sp) lsum += Lpart[(size_t)(b * nsp + sp) * NN + n];
      float g = gv / lsum;
      float ov[8] = {};
      for (int sp = 0; sp < nsp; ++sp) {
        const unsigned short* Op;
        size_t slab;
        if (sp == 0) { Op = OpartA; slab = (size_t)b * NN; }
        else { Op = OpartB; slab = (size_t)(b * (nsp - 1) + (sp - 1)) * NN; }
        short8 x = ld8(Op + (slab + n) * CC + cc);
#pragma unroll
        for (int j = 0; j < 8; ++j) ov[j] += bf2f(((unsigned short*)&x)[j]);
      }
      const unsigned short* lp = localT + ((size_t)b * NN + n) * CC + cc;
      short8 lv = ld8(lp);
      us4 r0, r1;
#pragma unroll
      for (int j = 0; j < 4; ++j) {
        r0[j] = f2bf(bf2f(((unsigned short*)&lv)[j]) + ov[j] * g);
        r1[j] = f2bf(bf2f(((unsigned short*)&lv)[j + 4]) + ov[j + 4] * g);
      }
      *reinterpret_cast<us4*>(&Xs[r][cc]) = r0;
      *reinterpret_cast<us4*>(&Xs[r][cc + 4]) = r1;
    }
  } else {
#pragma unroll
    for (int p = 0; p < 8; ++p) {
      int r = p * 8 + (tid >> 5), c = (tid & 31) * 8;
      *reinterpret_cast<uint4*>(&Xs[r][c]) =
          *reinterpret_cast<const uint4*>(fusedT + ((size_t)b * NN + n0 + r) * CC + c);
    }
  }
  int obase = o0 + wave * 32;
  short8 af[16];
#pragma unroll
  for (int t = 0; t < 16; ++t) af[t] = ld8(W + (size_t)(obase + l31) * CC + t * 16 + h * 8);
  __syncthreads();
  f32x16 acc[2] = {};
#pragma unroll
  for (int t = 0; t < 16; ++t) {
    short8 b0 = ld8(&Xs[l31][t * 16 + h * 8]);
    short8 b1 = ld8(&Xs[32 + l31][t * 16 + h * 8]);
    acc[0] = __builtin_amdgcn_mfma_f32_32x32x16_bf16(af[t], b0, acc[0], 0, 0, 0);
    acc[1] = __builtin_amdgcn_mfma_f32_32x32x16_bf16(af[t], b1, acc[1], 0, 0, 0);
  }
#pragma unroll
  for (int nt = 0; nt < 2; ++nt)
#pragma unroll
    for (int reg = 0; reg < 16; ++reg) {
      int o = obase + rowmap(reg, h);
      int n = n0 + nt * 32 + l31;
      out[((size_t)b * CC + o) * NN + n] = acc[nt][reg] + ob[o];
    }
}

// ---------------------------------------------------------------------------- launch
extern "C" void kernel_launch(void* const* d_in, const int* in_sizes, int n_in,
                              void* d_out, int out_size, void* d_ws, size_t ws_size,
                              hipStream_t stream) {
  const float* xs  = (const float*)d_in[0];
  const float* xo  = (const float*)d_in[1];
  const float* qw  = (const float*)d_in[2];
  const float* qb  = (const float*)d_in[3];
  const float* kvw = (const float*)d_in[4];
  const float* kvb = (const float*)d_in[5];
  const float* g1w = (const float*)d_in[6];
  const float* g1b = (const float*)d_in[7];
  const float* g2w = (const float*)d_in[8];
  const float* g2b = (const float*)d_in[9];
  const float* dww = (const float*)d_in[10];
  const float* dwb = (const float*)d_in[11];
  const float* bng = (const float*)d_in[12];
  const float* bnb = (const float*)d_in[13];
  const float* bnm = (const float*)d_in[14];
  const float* bnv = (const float*)d_in[15];
  const float* ow  = (const float*)d_in[16];
  const float* ob  = (const float*)d_in[17];
  float* out = (float*)d_out;
  char* ws = (char*)d_ws;

  const size_t SZ  = (size_t)BB * NN * CC * 2;            // 8 MB bf16 tensor
  const size_t SZ8 = (size_t)BB * NN * CC;                // 4 MB fp8 tensor
  unsigned short* XtS    = (unsigned short*)(ws);
  unsigned short* XtO    = (unsigned short*)(ws + SZ);
  unsigned short* localT = (unsigned short*)(ws + 2 * SZ);
  unsigned char*  Qt8    = (unsigned char*)(ws + 3 * SZ);
  unsigned char*  Kt8    = (unsigned char*)(ws + 3 * SZ + SZ8);
  unsigned char*  Vv8    = (unsigned char*)(ws + 3 * SZ + 2 * SZ8);
  unsigned short* Wb     = (unsigned short*)(ws + 3 * SZ + 3 * SZ8);   // 512 KB
  float* psumA = (float*)(ws + 3 * SZ + 3 * SZ8 + 524288);             // 256 KB
  float* gate  = (float*)(ws + 3 * SZ + 3 * SZ8 + 524288 + 262144);    // 16 B
  size_t tail  = 3 * SZ + 3 * SZ8 + 524288 + 262144 + 4096;
  float* Lpart = (float*)(ws + tail);                                  // 256 KB
  // Opart split-0 slab aliases XtO (dead after k_qkv); remaining slabs in tail.
  unsigned short* OpartA = XtO;
  unsigned short* OpartB = (unsigned short*)(ws + tail + 262144);      // (S-1)*8 MB
  unsigned short* fusedT = XtS;                                        // dead after k_qkv

  size_t base = tail + 262144;
  int S = 1;
  if (ws_size >= base + 2ull * SZ) S = 3;          // 768 blocks = 3/CU
  else if (ws_size >= base + 1ull * SZ) S = 2;

  k_pre<<<dim3(4, 64, 9), 256, 0, stream>>>(xs, xo, dww, dwb, bng, bnb, bnm, bnv,
                                            qw, kvw, ow, XtS, XtO, localT, psumA, Wb);
  k_qkv<<<dim3(64, 4, 4), 256, 0, stream>>>(XtS, XtO, Wb, qb, kvb, psumA,
                                            g1w, g1b, g2w, g2b, Qt8, Kt8, Vv8, gate);
  k_flash8<<<dim3(256, S), 256, 0, stream>>>(Qt8, Kt8, Vv8, localT, gate, OpartA,
                                             OpartB, Lpart, fusedT);
  k_out<<<dim3(64, 2, 4), 256, 0, stream>>>(Wb + 196608, ob, gate, localT,
                                            OpartA, OpartB, Lpart, fusedT, out, S);
}